// Round 9
// baseline (144.509 us; speedup 1.0000x reference)
//
#include <hip/hip_runtime.h>
#include <hip/hip_bf16.h>

namespace {

constexpr int T_DIM = 16384;   // number of tiles
constexpr int NT    = 8;       // tiles per block -> grid = 2048

typedef __attribute__((ext_vector_type(8))) short bf16x8;
typedef __attribute__((ext_vector_type(4))) float f32x4;

__device__ inline short f2bf(float f) {
    union { __hip_bfloat16 h; short s; } u;
    u.h = __float2bfloat16(f);
    return u.s;
}

__device__ inline bf16x8 cvt8(f32x4 a, f32x4 b) {
    bf16x8 r;
    r[0] = f2bf(a[0]); r[1] = f2bf(a[1]); r[2] = f2bf(a[2]); r[3] = f2bf(a[3]);
    r[4] = f2bf(b[0]); r[5] = f2bf(b[1]); r[6] = f2bf(b[2]); r[7] = f2bf(b[3]);
    return r;
}

} // namespace

// R2/R7 staging skeleton (best measured) with a halved compute phase:
//  - MFMA operands swapped (R8-verified): A = W1 (rows=j), B = x (cols=b),
//    D: col=l15=b_local, row=l4*4+r=j_local.
//  - j SPLIT BY WAVE: wave w computes j in [16w,16w+16) for ALL 128 b ->
//    each wave reads only its j-quarter of the LDS tile (4 ds_read_b128
//    vs 16), converts it once (16 cvt vs 64), and the j-reduction is
//    4-in-lane + 2 shfls (16 shfls/tile vs 32).
//  - cross-wave j-sum via double-buffered LDS partials [2][4][128] (4 KB),
//    reduced one tile late by threads<128 under the EXISTING barrier.
//  - x in registers (64 VGPR, loop-invariant). Loop fully unrolled: all
//    register indices static (rule #20). LDS 36 KB -> 4 blocks/CU.
__global__ __launch_bounds__(256, 4) void fgbn_kernel(
    const float* __restrict__ x,
    const float* __restrict__ W1,
    const float* __restrict__ b1,
    const float* __restrict__ W2,
    const float* __restrict__ b2,
    float* __restrict__ out)
{
    __shared__ float tile[2][4096];     // 2 x 16 KB f32 W1 tiles
    __shared__ float part[2][4][128];   // per-wave j-partials, dbuf

    const int tid  = threadIdx.x;
    const int lane = tid & 63;
    const int wave = tid >> 6;
    const int l15  = lane & 15;
    const int l4   = lane >> 4;
    const int t0   = blockIdx.x * NT;

    // x as B-fragments: B[k=8*l4+e][col=l15], b = bf*16+l15, k' = ks*32+k.
    bf16x8 xb[8][2];
    #pragma unroll
    for (int bf = 0; bf < 8; ++bf) {
        #pragma unroll
        for (int ks = 0; ks < 2; ++ks) {
            const float* src = x + (bf * 16 + l15) * 64 + ks * 32 + l4 * 8;
            xb[bf][ks] = cvt8(*reinterpret_cast<const f32x4*>(src),
                              *reinterpret_cast<const f32x4*>(src + 4));
        }
    }

    // One 16 KB W1 tile -> tile[buf]; 4 x 16B DMA per thread (R7-identical).
    // Swizzle (both-sides rule): LDS dest linear, global SOURCE chunk
    // pre-swizzled g = c ^ ((c>>4)&7); fragment reads apply the same XOR.
    auto stage = [&](int buf, int t) {
        const char* w1t = (const char*)W1 + (size_t)t * 16384;
        #pragma unroll
        for (int it = 0; it < 4; ++it) {
            const int c = wave * 256 + it * 64 + lane;
            const int g = c ^ ((c >> 4) & 7);
            __builtin_amdgcn_global_load_lds(
                (const __attribute__((address_space(1))) unsigned int*)(w1t + (size_t)g * 16),
                (__attribute__((address_space(3))) unsigned int*)&tile[buf][c * 4],
                16, 0, 0);
        }
    };

    // Per-lane b1/W2 quads for this wave's j-quad: j = wave*16 + l4*4 + r.
    f32x4 b1q = *reinterpret_cast<const f32x4*>(b1 + t0 * 64 + wave * 16 + l4 * 4);
    f32x4 w2q = *reinterpret_cast<const f32x4*>(W2 + t0 * 64 + wave * 16 + l4 * 4);

    stage(0, t0);
    __syncthreads();

    float yreg[NT];   // thread tid<128 accumulates y[b=tid, t0+ti]

    #pragma unroll
    for (int ti = 0; ti < NT; ++ti) {
        const int t = t0 + ti;
        const bool more = (ti + 1 < NT);

        // 1. Issue DMA for tile ti+1 + prefetch its b1/W2 quads.
        f32x4 b1n, w2n;
        if (more) {
            stage((ti + 1) & 1, t + 1);
            b1n = *reinterpret_cast<const f32x4*>(b1 + (t + 1) * 64 + wave * 16 + l4 * 4);
            w2n = *reinterpret_cast<const f32x4*>(W2 + (t + 1) * 64 + wave * 16 + l4 * 4);
        }

        // 2. Reduce PREVIOUS tile's partials (threads<128; parity (ti-1)&1).
        if (ti > 0 && tid < 128) {
            const int p = (ti - 1) & 1;
            const float v = part[p][0][tid] + part[p][1][tid] +
                            part[p][2][tid] + part[p][3][tid];
            yreg[ti - 1] = 2.f * (v + b2[t - 1]);
        }

        // 3. Compute tile ti: this wave's j-quarter only.
        const float* lbuf = tile[ti & 1];
        const int j  = wave * 16 + l15;
        const int sw = j & 7;
        bf16x8 a[2];
        #pragma unroll
        for (int ks = 0; ks < 2; ++ks) {
            const int c0 = j * 16 + ks * 8 + l4 * 2;
            a[ks] = cvt8(*reinterpret_cast<const f32x4*>(&lbuf[(c0 ^ sw) * 4]),
                         *reinterpret_cast<const f32x4*>(&lbuf[((c0 + 1) ^ sw) * 4]));
        }

        #pragma unroll
        for (int bf = 0; bf < 8; ++bf) {
            f32x4 acc = (f32x4){0.f, 0.f, 0.f, 0.f};
            acc = __builtin_amdgcn_mfma_f32_16x16x32_bf16(a[0], xb[bf][0], acc, 0, 0, 0);
            acc = __builtin_amdgcn_mfma_f32_16x16x32_bf16(a[1], xb[bf][1], acc, 0, 0, 0);
            // In-lane relu-dot over r (j = wave*16 + l4*4 + r).
            float s = 0.f;
            #pragma unroll
            for (int r = 0; r < 4; ++r) {
                const float p = fmaxf(acc[r] + b1q[r], 0.f);
                s = fmaf(p, w2q[r], s);
            }
            // Cross-l4 j-reduction: 2 shfls; l4==0 lanes hold the 16-j sum.
            s += __shfl_xor(s, 16);
            s += __shfl_xor(s, 32);
            if (l4 == 0) part[ti & 1][wave][bf * 16 + l15] = s;
        }

        if (more) { b1q = b1n; w2q = w2n; }

        // 4. One barrier: drains DMA(ti+1) (RAW) + WAR on tile & partials.
        __syncthreads();
    }

    // Final reduce (tile NT-1) + coalesced-per-row store: thread b = tid
    // writes y[b, t0..t0+7] as two 16B stores (one 32B sector per row).
    if (tid < 128) {
        const int p = (NT - 1) & 1;
        const float v = part[p][0][tid] + part[p][1][tid] +
                        part[p][2][tid] + part[p][3][tid];
        yreg[NT - 1] = 2.f * (v + b2[t0 + NT - 1]);

        float* dst = out + (size_t)tid * T_DIM + t0;
        *reinterpret_cast<f32x4*>(dst)     = (f32x4){yreg[0], yreg[1], yreg[2], yreg[3]};
        *reinterpret_cast<f32x4*>(dst + 4) = (f32x4){yreg[4], yreg[5], yreg[6], yreg[7]};
    }
}

extern "C" void kernel_launch(void* const* d_in, const int* in_sizes, int n_in,
                              void* d_out, int out_size, void* d_ws, size_t ws_size,
                              hipStream_t stream) {
    const float* x  = (const float*)d_in[0];
    const float* W1 = (const float*)d_in[1];
    const float* b1 = (const float*)d_in[2];
    const float* W2 = (const float*)d_in[3];
    const float* b2 = (const float*)d_in[4];
    float* out = (float*)d_out;

    dim3 grid(T_DIM / NT);   // 2048 blocks
    dim3 block(256);
    hipLaunchKernelGGL(fgbn_kernel, grid, block, 0, stream,
                       x, W1, b1, W2, b2, out);
}

// Round 10
// 59.289 us; speedup vs baseline: 2.4373x; 2.4373x over previous
//
#include <hip/hip_runtime.h>
#include <hip/hip_bf16.h>

namespace {

constexpr int T_DIM = 16384;   // number of tiles
constexpr int NT    = 8;       // tiles per block -> grid = 2048
constexpr int YP    = 9;       // padded y_lds stride (conflict-free)

typedef __attribute__((ext_vector_type(8))) short bf16x8;
typedef __attribute__((ext_vector_type(4))) float f32x4;

__device__ inline short f2bf(float f) {
    union { __hip_bfloat16 h; short s; } u;
    u.h = __float2bfloat16(f);
    return u.s;
}

__device__ inline bf16x8 cvt8(f32x4 a, f32x4 b) {
    bf16x8 r;
    r[0] = f2bf(a[0]); r[1] = f2bf(a[1]); r[2] = f2bf(a[2]); r[3] = f2bf(a[3]);
    r[4] = f2bf(b[0]); r[5] = f2bf(b[1]); r[6] = f2bf(b[2]); r[7] = f2bf(b[3]);
    return r;
}

} // namespace

// R7 skeleton (best: 58-59us) with ONE change: MFMA operands swapped
// (R8-verified layout) so 16 j sit IN-LANE -> the stage-2 j-reduction is
// pure VALU + 2 shfls per bf (4 shfls/wave/tile vs R7's 32). The shfl
// butterfly was ~half the DS-pipe cost in the convoy model.
//  - A = W1 j-rows from LDS: SAME ds_read addresses/swizzle as R7.
//  - B = x in registers (xb[2][2], wave owns b in [32w,32w+32)).
//  - D: col=l15=b_local, row=4*l4+r=j_local (R8/R9-verified numerically).
//  - y transposed via 4.5KB padded y_lds; epilogue = 2x16B stores/row.
//  - staging DMA, swizzle, one __syncthreads/tile, NT=8, bounds(256,4):
//    byte-identical to R7.
__global__ __launch_bounds__(256, 4) void fgbn_kernel(
    const float* __restrict__ x,
    const float* __restrict__ W1,
    const float* __restrict__ b1,
    const float* __restrict__ W2,
    const float* __restrict__ b2,
    float* __restrict__ out)
{
    __shared__ float tile[2][4096];     // 2 x 16 KB f32 W1 tiles
    __shared__ float y_lds[128 * YP];   // y[b][tloc], padded -> 4.5 KB

    const int tid  = threadIdx.x;
    const int lane = tid & 63;
    const int wave = tid >> 6;
    const int l15  = lane & 15;
    const int l4   = lane >> 4;
    const int t0   = blockIdx.x * NT;

    // x as B-fragments: B[k=8*l4+e][col=l15], b = wave*32 + bf*16 + l15.
    bf16x8 xb[2][2];   // [bf][ks]
    #pragma unroll
    for (int bf = 0; bf < 2; ++bf) {
        #pragma unroll
        for (int ks = 0; ks < 2; ++ks) {
            const float* src = x + (wave * 32 + bf * 16 + l15) * 64 + ks * 32 + l4 * 8;
            xb[bf][ks] = cvt8(*reinterpret_cast<const f32x4*>(src),
                              *reinterpret_cast<const f32x4*>(src + 4));
        }
    }

    // One 16 KB W1 tile -> tile[buf]; 4 x 16B DMA per thread (R7-identical).
    auto stage = [&](int buf, int t) {
        const char* w1t = (const char*)W1 + (size_t)t * 16384;
        #pragma unroll
        for (int it = 0; it < 4; ++it) {
            const int c = wave * 256 + it * 64 + lane;
            const int g = c ^ ((c >> 4) & 7);
            __builtin_amdgcn_global_load_lds(
                (const __attribute__((address_space(1))) unsigned int*)(w1t + (size_t)g * 16),
                (__attribute__((address_space(3))) unsigned int*)&tile[buf][c * 4],
                16, 0, 0);
        }
    };

    stage(0, t0);
    __syncthreads();

    for (int ti = 0; ti < NT; ++ti) {
        const int t = t0 + ti;
        const bool more = (ti + 1 < NT);

        // 1. Issue DMA for tile ti+1 (in flight across compute + barrier).
        if (more) stage((ti + 1) & 1, t + 1);

        // 2. This tile's b1/W2 j-quads and b2 (issued now, consumed late --
        //    compiler hoists the loads, waits sit after the MFMAs).
        f32x4 b1q[4], w2q[4];
        #pragma unroll
        for (int nf = 0; nf < 4; ++nf) {
            b1q[nf] = *reinterpret_cast<const f32x4*>(b1 + t * 64 + nf * 16 + l4 * 4);
            w2q[nf] = *reinterpret_cast<const f32x4*>(W2 + t * 64 + nf * 16 + l4 * 4);
        }
        const float b2t = b2[t];

        // 3. Compute: per nf, A = W1 j-rows (LDS, same reads as R7), then
        //    fold relu-dot in-lane (j = nf*16 + 4*l4 + r). acc is transient.
        const float* lbuf = tile[ti & 1];
        float s0 = 0.f, s1 = 0.f;   // per-lane partial y for bf=0,1

        #pragma unroll
        for (int nf = 0; nf < 4; ++nf) {
            const int j  = nf * 16 + l15;
            const int sw = j & 7;
            bf16x8 a[2];
            #pragma unroll
            for (int ks = 0; ks < 2; ++ks) {
                const int c0 = j * 16 + ks * 8 + l4 * 2;
                a[ks] = cvt8(*reinterpret_cast<const f32x4*>(&lbuf[(c0 ^ sw) * 4]),
                             *reinterpret_cast<const f32x4*>(&lbuf[((c0 + 1) ^ sw) * 4]));
            }

            f32x4 acc0 = (f32x4){0.f, 0.f, 0.f, 0.f};
            f32x4 acc1 = (f32x4){0.f, 0.f, 0.f, 0.f};
            acc0 = __builtin_amdgcn_mfma_f32_16x16x32_bf16(a[0], xb[0][0], acc0, 0, 0, 0);
            acc0 = __builtin_amdgcn_mfma_f32_16x16x32_bf16(a[1], xb[0][1], acc0, 0, 0, 0);
            acc1 = __builtin_amdgcn_mfma_f32_16x16x32_bf16(a[0], xb[1][0], acc1, 0, 0, 0);
            acc1 = __builtin_amdgcn_mfma_f32_16x16x32_bf16(a[1], xb[1][1], acc1, 0, 0, 0);

            #pragma unroll
            for (int r = 0; r < 4; ++r) {
                const float p0 = fmaxf(acc0[r] + b1q[nf][r], 0.f);
                const float p1 = fmaxf(acc1[r] + b1q[nf][r], 0.f);
                s0 = fmaf(p0, w2q[nf][r], s0);
                s1 = fmaf(p1, w2q[nf][r], s1);
            }
        }

        // 4. Cross-l4 j-reduction: 2 shfls per bf (in-lane already has 16 j).
        s0 += __shfl_xor(s0, 16);
        s0 += __shfl_xor(s0, 32);
        s1 += __shfl_xor(s1, 16);
        s1 += __shfl_xor(s1, 32);
        if (l4 == 0) {
            y_lds[(wave * 32 + l15) * YP + ti]      = 2.f * (s0 + b2t);
            y_lds[(wave * 32 + 16 + l15) * YP + ti] = 2.f * (s1 + b2t);
        }

        // 5. One barrier: drains DMA(ti+1) (RAW) + WAR on tile[ti&1];
        //    also orders the final tile's y_lds writes before the epilogue.
        __syncthreads();
    }

    // Epilogue: thread b = tid < 128 writes y[b, t0..t0+7] as two 16B stores.
    if (tid < 128) {
        float v[NT];
        #pragma unroll
        for (int k = 0; k < NT; ++k) v[k] = y_lds[tid * YP + k];
        float* dst = out + (size_t)tid * T_DIM + t0;
        *reinterpret_cast<f32x4*>(dst)     = (f32x4){v[0], v[1], v[2], v[3]};
        *reinterpret_cast<f32x4*>(dst + 4) = (f32x4){v[4], v[5], v[6], v[7]};
    }
}

extern "C" void kernel_launch(void* const* d_in, const int* in_sizes, int n_in,
                              void* d_out, int out_size, void* d_ws, size_t ws_size,
                              hipStream_t stream) {
    const float* x  = (const float*)d_in[0];
    const float* W1 = (const float*)d_in[1];
    const float* b1 = (const float*)d_in[2];
    const float* W2 = (const float*)d_in[3];
    const float* b2 = (const float*)d_in[4];
    float* out = (float*)d_out;

    dim3 grid(T_DIM / NT);   // 2048 blocks
    dim3 block(256);
    hipLaunchKernelGGL(fgbn_kernel, grid, block, 0, stream,
                       x, W1, b1, W2, b2, out);
}